// Round 9
// baseline (329.242 us; speedup 1.0000x reference)
//
#include <hip/hip_runtime.h>
#include <hip/hip_bf16.h>

// DotProductAttention: B=4, N=4096, E=1024, D=256. f32 in/out.
// Pipeline: cast/prep -> QKV GEMM (z=3) -> VT GEMM -> k_score (packed
// lower-tri P~, rowsum l) -> k_pv (O = P~ @ V / l).
// R11 (331us): XCD-grouped k_pv + dbuf vmcnt(4); k_pv 112us, Mfma 27%.
// R12 FAILED: swizzle null at BK=32 (64B rows: structural). R13 FAILED:
// LDS-free TA-bound.
// R15 WIN (313.5us): k_pv 256x128 BK=64 3-buf counted-vmcnt + swizzle ->
// 86.9us, Mfma 34%, bank-conflicts 0. But 1 block/CU (144KB LDS) = one
// barrier domain -> lockstep drain exposed (LDS ~50%, HBM ~32%, Mfma 34%:
// latency-bound, not resource-bound).
// R16: k_pv 128x128 BK=64, 2-buf (64KB) -> TWO blocks/CU = two independent
// barrier domains (m97's implicit cross-block overlap). Keeps the
// conflict-free (row&7)<<4 swizzle (needs 128B rows) + counted vmcnt(8)
// depth-1 schedule (R11-proven shape). 128-row qt granularity: K-length
// (qt+1)*128 divisible by 64 -> no zero-tail, no skip logic. Pair-chains
// (pr,31-pr): every block exactly 66 K-tiles. l=b*128+dv*16+pr -> the 8
// dv-siblings sharing a P stream share l%8 -> one XCD.
// k_score/GEMMs/prep: R15 verbatim.

typedef __hip_bfloat16 bf16;
typedef __bf16 bf16x4 __attribute__((ext_vector_type(4)));
typedef __bf16 bf16x8 __attribute__((ext_vector_type(8)));
typedef float f32x4 __attribute__((ext_vector_type(4)));

#define BK 32
#define HALF_BYTES 8192   // 128*BK*2 bytes per LDS buffer half (R11 path)
#define PVBUF 32768       // k_pv: A[128][64] (16KB) + B[128][64] (16KB)

__device__ __forceinline__ void gload_lds16(const bf16* g, bf16* l) {
    __builtin_amdgcn_global_load_lds(
        (const __attribute__((address_space(1))) unsigned int*)g,
        (__attribute__((address_space(3))) unsigned int*)l, 16, 0, 0);
}

__device__ __forceinline__ void zero_acc(f32x4 acc[4][4]) {
#pragma unroll
    for (int mi = 0; mi < 4; ++mi)
#pragma unroll
        for (int ni = 0; ni < 4; ++ni) {
            f32x4 zf = {0.f, 0.f, 0.f, 0.f};
            acc[mi][ni] = zf;
        }
}

// ---------- LDS-staged 128x128 tile (R11, verbatim): dense GEMMs + score ---
__device__ __forceinline__ void mm_tile(const bf16* __restrict__ Ablk,
                                        const bf16* __restrict__ Bblk,
                                        int lda, int ldb, int kiters,
                                        bf16* As, bf16* Bs, f32x4 acc[4][4]) {
    const int tid  = threadIdx.x;
    const int wave = tid >> 6;
    const int lane = tid & 63;

    const int F0 = wave * 2048 + lane * 16;  // byte offset; 4 waves cover 8KB
    const int F1 = F0 + 1024;
    const int r0 = F0 >> 6, c0 = (F0 & 63) >> 1;  // 64B (=32 bf16) per row
    const int r1 = F1 >> 6, c1 = (F1 & 63) >> 1;
    const bf16* ga0 = Ablk + (size_t)r0 * lda + c0;
    const bf16* ga1 = Ablk + (size_t)r1 * lda + c1;
    const bf16* gb0 = Bblk + (size_t)r0 * ldb + c0;
    const bf16* gb1 = Bblk + (size_t)r1 * ldb + c1;

    const int waveM = wave >> 1, waveN = wave & 1;
    const int mrow = waveM * 64 + (lane & 15);
    const int nrow = waveN * 64 + (lane & 15);
    const int koff = (lane >> 4) * 8;

#define STAGE_TO(buf)                                                        \
    {                                                                        \
        char* Ad = (char*)As + (buf) * HALF_BYTES;                           \
        char* Bd = (char*)Bs + (buf) * HALF_BYTES;                           \
        gload_lds16(ga0, (bf16*)(Ad + F0));                                  \
        gload_lds16(ga1, (bf16*)(Ad + F1));                                  \
        gload_lds16(gb0, (bf16*)(Bd + F0));                                  \
        gload_lds16(gb1, (bf16*)(Bd + F1));                                  \
        ga0 += BK; ga1 += BK; gb0 += BK; gb1 += BK;                          \
    }

    STAGE_TO(0);
    int cur = 0;
    for (int it = 0; it < kiters - 1; ++it) {
        const int nxt = cur ^ 1;
        STAGE_TO(nxt);

        __builtin_amdgcn_sched_barrier(0);
        asm volatile("s_waitcnt vmcnt(4)" ::: "memory");
        __builtin_amdgcn_sched_barrier(0);
        __builtin_amdgcn_s_barrier();
        __builtin_amdgcn_sched_barrier(0);

        {
            const bf16* Ar = (const bf16*)((const char*)As + cur * HALF_BYTES);
            const bf16* Br = (const bf16*)((const char*)Bs + cur * HALF_BYTES);
            bf16x8 af[4], bfr[4];
#pragma unroll
            for (int mi = 0; mi < 4; ++mi)
                af[mi] = *(const bf16x8*)(Ar + (mrow + mi * 16) * BK + koff);
#pragma unroll
            for (int ni = 0; ni < 4; ++ni)
                bfr[ni] = *(const bf16x8*)(Br + (nrow + ni * 16) * BK + koff);
#pragma unroll
            for (int mi = 0; mi < 4; ++mi)
#pragma unroll
                for (int ni = 0; ni < 4; ++ni)
                    acc[mi][ni] = __builtin_amdgcn_mfma_f32_16x16x32_bf16(
                        af[mi], bfr[ni], acc[mi][ni], 0, 0, 0);
        }

        __builtin_amdgcn_sched_barrier(0);
        asm volatile("s_waitcnt lgkmcnt(0)" ::: "memory");
        __builtin_amdgcn_sched_barrier(0);
        __builtin_amdgcn_s_barrier();
        __builtin_amdgcn_sched_barrier(0);
        cur = nxt;
    }

    __builtin_amdgcn_sched_barrier(0);
    asm volatile("s_waitcnt vmcnt(0)" ::: "memory");
    __builtin_amdgcn_sched_barrier(0);
    __builtin_amdgcn_s_barrier();
    __builtin_amdgcn_sched_barrier(0);
    {
        const bf16* Ar = (const bf16*)((const char*)As + cur * HALF_BYTES);
        const bf16* Br = (const bf16*)((const char*)Bs + cur * HALF_BYTES);
        bf16x8 af[4], bfr[4];
#pragma unroll
        for (int mi = 0; mi < 4; ++mi)
            af[mi] = *(const bf16x8*)(Ar + (mrow + mi * 16) * BK + koff);
#pragma unroll
        for (int ni = 0; ni < 4; ++ni)
            bfr[ni] = *(const bf16x8*)(Br + (nrow + ni * 16) * BK + koff);
#pragma unroll
        for (int mi = 0; mi < 4; ++mi)
#pragma unroll
            for (int ni = 0; ni < 4; ++ni)
                acc[mi][ni] = __builtin_amdgcn_mfma_f32_16x16x32_bf16(
                    af[mi], bfr[ni], acc[mi][ni], 0, 0, 0);
    }
#undef STAGE_TO
}

// ---------------- plain GEMM: C[m][n] = A*BT^T, bf16 store -----------------
__global__ __launch_bounds__(256, 2) void k_gemm_plain(
    const bf16* __restrict__ A, long long aBatch,
    const bf16* __restrict__ BT, long long bBatch,
    bf16* __restrict__ C, long long cBatch,
    int lda, int ldb, int ldc, int kiters) {
    __shared__ __align__(16) bf16 As[2 * 128 * BK];
    __shared__ __align__(16) bf16 Bs[2 * 128 * BK];
    const int nBase = blockIdx.x * 128;
    const int mBase = blockIdx.y * 128;
    const int z = blockIdx.z;
    const bf16* Ab = A + (size_t)z * aBatch + (size_t)mBase * lda;
    const bf16* Bb = BT + (size_t)z * bBatch + (size_t)nBase * ldb;

    f32x4 acc[4][4];
    zero_acc(acc);
    mm_tile(Ab, Bb, lda, ldb, kiters, As, Bs, acc);

    const int tid = threadIdx.x, wave = tid >> 6, lane = tid & 63;
    const int waveM = wave >> 1, waveN = wave & 1;
    const int quad = lane >> 4, cno = lane & 15;
    bf16* Cb = C + (size_t)z * cBatch;
#pragma unroll
    for (int mi = 0; mi < 4; ++mi) {
        int row0 = mBase + waveM * 64 + mi * 16 + quad * 4;
#pragma unroll
        for (int ni = 0; ni < 4; ++ni) {
            int col = nBase + waveN * 64 + ni * 16 + cno;
#pragma unroll
            for (int r = 0; r < 4; ++r)
                Cb[(size_t)(row0 + r) * ldc + col] = __float2bfloat16(acc[mi][ni][r]);
        }
    }
}

// ---------------- score: packed P~ = exp(mask(Q K^T / 16)) -----------------
// R11 verbatim. 528 lower-tri tiles/batch; P packed: block-row qt starts at
// element 16384*tri(qt), pitch (qt+1)*128. Row sums -> lsum atomics.
#define P_BATCH 8650752ll  // 528 * 16384 elements per batch
__global__ __launch_bounds__(256, 2) void k_score(
    const bf16* __restrict__ Qm, const bf16* __restrict__ Km,
    bf16* __restrict__ P, float* __restrict__ lsum) {
    const int f = blockIdx.x, b = blockIdx.z;
    int qt = (int)((sqrtf(8.f * (float)f + 1.f) - 1.f) * 0.5f);
    while ((qt + 1) * (qt + 2) / 2 <= f) ++qt;
    while (qt * (qt + 1) / 2 > f) --qt;
    const int kt = f - qt * (qt + 1) / 2;

    __shared__ __align__(16) bf16 As[2 * 128 * BK];
    __shared__ __align__(16) bf16 Bs[2 * 128 * BK];

    const bf16* Ab = Qm + ((size_t)b * 4096 + (size_t)qt * 128) * 256;
    const bf16* Bb = Km + ((size_t)b * 4096 + (size_t)kt * 128) * 256;

    f32x4 acc[4][4];
    zero_acc(acc);
    mm_tile(Ab, Bb, 256, 256, 256 / BK, As, Bs, acc);

    const int tid = threadIdx.x, wave = tid >> 6, lane = tid & 63;
    const int waveM = wave >> 1, waveN = wave & 1;
    const int quad = lane >> 4, cno = lane & 15;
    const int pitch = (qt + 1) * 128;
    bf16* Pb = P + b * P_BATCH + (size_t)16384 * (qt * (qt + 1) / 2);
    float* lb = lsum + b * 4096;
#pragma unroll
    for (int mi = 0; mi < 4; ++mi) {
        const int lq0 = waveM * 64 + mi * 16 + quad * 4;
        float rs[4] = {0.f, 0.f, 0.f, 0.f};
#pragma unroll
        for (int ni = 0; ni < 4; ++ni) {
            const int cn = waveN * 64 + ni * 16 + cno;
            const int gk = kt * 128 + cn;
#pragma unroll
            for (int r = 0; r < 4; ++r) {
                const int gq = qt * 128 + lq0 + r;
                float s = acc[mi][ni][r] * 0.0625f;  // 1/sqrt(256)
                // ref quirk: masked OR exactly-zero score -> exp = 0
                float p = (gk <= gq && s != 0.0f) ? __expf(s) : 0.0f;
                bf16 pb = __float2bfloat16(p);
                Pb[(size_t)(lq0 + r) * pitch + gk] = pb;
                rs[r] += __bfloat162float(pb);  // sum what PV multiplies
            }
        }
#pragma unroll
        for (int r = 0; r < 4; ++r) {
            float v = rs[r];
            v += __shfl_xor(v, 1);
            v += __shfl_xor(v, 2);
            v += __shfl_xor(v, 4);
            v += __shfl_xor(v, 8);
            if (cno == 0) atomicAdd(&lb[qt * 128 + lq0 + r], v);
        }
    }
}

// --------------- PV GEMM: 128x128 tile, BK=64, 2 blocks/CU -----------------
// Grid 512 blocks x 256 thr (4 waves 2Mx2N). l = b*128 + dv*16 + pr:
// pair (pr,31-pr) -> exactly 66 K-tiles/block (uniform, no tail); the 8
// dv-siblings sharing a P stream share l%8=pr%8 -> one XCD. 2-buf 64KB LDS
// -> 2 blocks/CU = two barrier domains (cross-block drain overlap).
// Depth-1 stage-ahead, counted vmcnt(8) (never 0 mid-loop). (row&7)<<4
// swizzle on 128B rows -> conflict-free b128. setprio around MFMA.
__global__ __launch_bounds__(256, 2) void k_pv(
    const bf16* __restrict__ Pm, const bf16* __restrict__ VT,
    const float* __restrict__ lsum, float* __restrict__ Out) {
    __shared__ __align__(16) char lds[2 * PVBUF];
    const int l = blockIdx.x;
    const int pr = l & 15, dv = (l >> 4) & 7, b = l >> 7;
    const int tid = threadIdx.x;
    const int wave = tid >> 6, lane = tid & 63;
    const int waveM = wave >> 1, waveN = wave & 1;  // 2M x 2N
    const int quad = lane >> 4, cno = lane & 15;

    // staging: 256 thr x 16B = 4KB per segment; 32 rows/segment, 128B rows
    const int srow = tid >> 3;                                  // 0..31
    const int swzEl = (((tid & 7) * 16) ^ ((srow & 7) << 4)) >> 1;
    const int F = tid * 16;

    const bf16* VTb = VT + ((size_t)b * 1024 + dv * 128) * 4096;
    float* Ob = Out + (size_t)b * 4096 * 1024;
    const float* lb = lsum + b * 4096;

    // fragment read offsets (swizzled): row*128B + ((kk*64+quad*16)^rswz)
    const int rswz = (lane & 7) << 4;
    int offA[4], offB[4], colk[2];
#pragma unroll
    for (int mi = 0; mi < 4; ++mi)
        offA[mi] = (waveM * 64 + mi * 16 + (lane & 15)) * 128;
#pragma unroll
    for (int ni = 0; ni < 4; ++ni)
        offB[ni] = (waveN * 64 + ni * 16 + (lane & 15)) * 128;
    colk[0] = (quad * 16) ^ rswz;
    colk[1] = (64 + quad * 16) ^ rswz;

#pragma unroll 1
    for (int c = 0; c < 2; ++c) {
        const int qt = c ? (31 - pr) : pr;
        const int pitch = (qt + 1) * 128;     // P row pitch (elements) = K
        const bf16* base = Pm + (size_t)b * P_BATCH
                           + (size_t)16384 * (qt * (qt + 1) / 2);
        const int nt = (qt + 1) * 2;          // K-tiles of 64 (no tail)

        const bf16* a0 = base + (size_t)srow * pitch + swzEl;
        const bf16* a1 = base + (size_t)(32 + srow) * pitch + swzEl;
        const bf16* a2 = base + (size_t)(64 + srow) * pitch + swzEl;
        const bf16* a3 = base + (size_t)(96 + srow) * pitch + swzEl;
        const bf16* b0 = VTb + (size_t)srow * 4096 + swzEl;
        const bf16* b1 = VTb + (size_t)(32 + srow) * 4096 + swzEl;
        const bf16* b2 = VTb + (size_t)(64 + srow) * 4096 + swzEl;
        const bf16* b3 = VTb + (size_t)(96 + srow) * 4096 + swzEl;

        // protect previous chain's last-tile LDS reads from our staging
        __builtin_amdgcn_s_barrier();

#define STG(bi)                                                              \
    {                                                                        \
        char* Ad = lds + (bi) * PVBUF;                                       \
        char* Bd = Ad + 16384;                                               \
        gload_lds16(a0, (bf16*)(Ad + F));                                    \
        gload_lds16(a1, (bf16*)(Ad + 4096 + F));                             \
        gload_lds16(a2, (bf16*)(Ad + 8192 + F));                             \
        gload_lds16(a3, (bf16*)(Ad + 12288 + F));                            \
        gload_lds16(b0, (bf16*)(Bd + F));                                    \
        gload_lds16(b1, (bf16*)(Bd + 4096 + F));                             \
        gload_lds16(b2, (bf16*)(Bd + 8192 + F));                             \
        gload_lds16(b3, (bf16*)(Bd + 12288 + F));                            \
        a0 += 64; a1 += 64; a2 += 64; a3 += 64;                              \
        b0 += 64; b1 += 64; b2 += 64; b3 += 64;                              \
    }

#define COMPUTE(bi)                                                          \
    {                                                                        \
        const char* Ab = lds + (bi) * PVBUF;                                 \
        const char* Bd = Ab + 16384;                                         \
        _Pragma("unroll")                                                    \
        for (int kk = 0; kk < 2; ++kk) {                                     \
            bf16x8 af[4], bfv[4];                                            \
            _Pragma("unroll")                                                \
            for (int mi = 0; mi < 4; ++mi)                                   \
                af[mi] = *(const bf16x8*)(Ab + offA[mi] + colk[kk]);         \
            _Pragma("unroll")                                                \
            for (int ni = 0; ni < 4; ++ni)                                   \
                bfv[ni] = *(const bf16x8*)(Bd + offB[ni] + colk[kk]);        \
            __builtin_amdgcn_s_setprio(1);                                   \
            _Pragma("unroll")                                                \
            for (int mi = 0; mi < 4; ++mi)                                   \
                _Pragma("unroll")                                            \
                for (int ni = 0; ni < 4; ++ni)                               \
                    acc[mi][ni] = __builtin_amdgcn_mfma_f32_16x16x32_bf16(   \
                        af[mi], bfv[ni], acc[mi][ni], 0, 0, 0);              \
            __builtin_amdgcn_s_setprio(0);                                   \
        }                                                                    \
    }

        f32x4 acc[4][4];
        zero_acc(acc);
        STG(0);
        int cur = 0;
        for (int t = 0; t < nt - 1; ++t) {
            STG(cur ^ 1);
            __builtin_amdgcn_sched_barrier(0);
            asm volatile("s_waitcnt vmcnt(8)" ::: "memory");
            __builtin_amdgcn_sched_barrier(0);
            __builtin_amdgcn_s_barrier();
            __builtin_amdgcn_sched_barrier(0);
            COMPUTE(cur);
            __builtin_amdgcn_sched_barrier(0);
            asm volatile("s_waitcnt lgkmcnt(0)" ::: "memory");
            __builtin_amdgcn_sched_barrier(0);
            __builtin_amdgcn_s_barrier();
            __builtin_amdgcn_sched_barrier(0);
            cur ^= 1;
        }
        __builtin_amdgcn_sched_barrier(0);
        asm volatile("s_waitcnt vmcnt(0)" ::: "memory");
        __builtin_amdgcn_sched_barrier(0);
        __builtin_amdgcn_s_barrier();
        __builtin_amdgcn_sched_barrier(0);
        COMPUTE(cur);
#undef STG
#undef COMPUTE

        // epilogue: O[gq, col] = acc / l
#pragma unroll
        for (int mi = 0; mi < 4; ++mi) {
            const int lq0 = waveM * 64 + mi * 16 + quad * 4;
#pragma unroll
            for (int r = 0; r < 4; ++r) {
                const int gq = qt * 128 + lq0 + r;
                const float inv = 1.0f / lb[gq];
#pragma unroll
                for (int ni = 0; ni < 4; ++ni) {
                    const int col = dv * 128 + waveN * 64 + ni * 16 + cno;
                    Ob[(size_t)gq * 1024 + col] = acc[mi][ni][r] * inv;
                }
            }
        }
    }
}

// ----------------------------- prep kernels (f32 inputs) -------------------
__global__ void k_cast(const float4* __restrict__ in, bf16* __restrict__ out,
                       int n4) {
    int i = blockIdx.x * 256 + threadIdx.x;
    if (i >= n4) return;
    float4 v = in[i];
    bf16x4 o;
    o[0] = (__bf16)v.x; o[1] = (__bf16)v.y; o[2] = (__bf16)v.z; o[3] = (__bf16)v.w;
    *(bf16x4*)(out + 4 * (size_t)i) = o;
}

// out[idx] = in[(idx & mask) * tstride + (idx >> shift)]; n = total elements.
__global__ void k_transpose(const float* __restrict__ in, bf16* __restrict__ out,
                            int n, int mask, int shift, int tstride) {
    int idx = blockIdx.x * 256 + threadIdx.x;
    if (idx >= n) return;
    out[idx] = __float2bfloat16(in[(size_t)(idx & mask) * tstride + (idx >> shift)]);
}

extern "C" void kernel_launch(void* const* d_in, const int* in_sizes, int n_in,
                              void* d_out, int out_size, void* d_ws, size_t ws_size,
                              hipStream_t stream) {
    const int B = 4, N = 4096, E = 1024, D = 256;
    const float* X   = (const float*)d_in[0];  // [4,4096,1024]
    const float* Wq  = (const float*)d_in[1];  // [1024,256]
    const float* Wk  = (const float*)d_in[2];  // [1024,256]
    const float* Wvd = (const float*)d_in[3];  // [1024,256]
    const float* Wvu = (const float*)d_in[4];  // [256,1024]
    float* out = (float*)d_out;                // [4,4096,1024]

    // ---- workspace layout (122 MiB + 64 KiB; P overlays dead Xb/weights) ---
    const long long MiB = 1ll << 20;
    char* ws = (char*)d_ws;
    bf16* Xb     = (bf16*)(ws);                       // [ 0,32)  [16384][1024]
    bf16* WqT    = (bf16*)(ws + 32 * MiB);            // 512 KiB  [256][1024]
    bf16* WkT    = (bf16*)(ws + 32 * MiB + 524288);   // 512 KiB (contiguous!)
    bf16* WvdT   = (bf16*)(ws + 32 * MiB + 1048576);  // 512 KiB (contiguous!)
    bf16* WvupT  = (bf16*)(ws + 32 * MiB + 1572864);  // 512 KiB  [1024][256]
    bf16* P      = (bf16*)(ws);                       // [ 0,66)  packed tri
    bf16* Qm     = (bf16*)(ws + 66 * MiB);            // [66,74)  [16384][256]
    bf16* Km     = (bf16*)(ws + 74 * MiB);            // [74,82)  = Qm+cBatch
    bf16* Vd     = (bf16*)(ws + 82 * MiB);            // [82,90)  = Qm+2*cBatch
    bf16* VT     = (bf16*)(ws + 90 * MiB);            // [90,122) [4][1024][4096]
    float* lsum  = (float*)(ws + 122 * MiB);          // 64 KiB   [4][4096]
    // lifetime: Xb/W*T dead before k_score writes P (alias [0,66) ok)

    const int n4 = B * N * E / 4;
    k_cast<<<(n4 + 255) / 256, 256, 0, stream>>>((const float4*)X, Xb, n4);
    // WqT[d][e] = Wq[e][d]: idx=d*1024+e -> e=idx&1023, d=idx>>10, stride 256
    k_transpose<<<1024, 256, 0, stream>>>(Wq,  WqT,  E * D, 1023, 10, 256);
    k_transpose<<<1024, 256, 0, stream>>>(Wk,  WkT,  E * D, 1023, 10, 256);
    k_transpose<<<1024, 256, 0, stream>>>(Wvd, WvdT, E * D, 1023, 10, 256);
    // WvupT[dv][d] = Wvu[d][dv]: idx=dv*256+d -> d=idx&255, dv=idx>>8, str 1024
    k_transpose<<<1024, 256, 0, stream>>>(Wvu, WvupT, D * E, 255, 8, 1024);
    hipMemsetAsync(lsum, 0, (size_t)B * N * sizeof(float), stream);

    // Q,K,Vd = Xb @ {Wq,Wk,Wvdown}  (z=3: outputs at Qm + z*8MiB)
    k_gemm_plain<<<dim3(D / 128, (B * N) / 128, 3), 256, 0, stream>>>(
        Xb, 0, WqT, (long long)D * E, Qm, (long long)B * N * D,
        E, E, D, E / BK);

    // VT[b][dv][n] = sum_d WvupT[dv][d] * Vd[b][n][d]   (K=256)
    k_gemm_plain<<<dim3(N / 128, E / 128, B), 256, 0, stream>>>(
        WvupT, 0, Vd, (long long)N * D, VT, (long long)E * N,
        D, D, N, D / BK);

    // P~ = exp(mask(Q K^T / 16)) packed; row sums -> lsum (528 tri tiles/b)
    k_score<<<dim3(528, 1, B), 256, 0, stream>>>(Qm, Km, P, lsum);

    // Out = (P~ @ V) / l  (128x128 BK=64, 2 blocks/CU, pair-balanced,
    // XCD-grouped)
    k_pv<<<dim3(512, 1, 1), 256, 0, stream>>>(P, VT, lsum, out);
}